// Round 1
// baseline (180.476 us; speedup 1.0000x reference)
//
#include <hip/hip_runtime.h>
#include <hip/hip_bf16.h>

#define N_NODES 50000
#define N_EDGES 800000
#define FEAT 64
#define NRELS 8
#define NBUCK 196         // ceil(50000/256) buckets of 256 dst nodes (dst >> 8)
#define EPB 2048          // edges per bfill block
#define NBP 391           // ceil(E / EPB)
#define BCAP 5120         // fixed slots per bucket (mean 4082 + 16 sigma)
#define FB_BLOCKS 782     // ceil(N / 64) feat->bf16 rider blocks in mid
#define NPB 32            // dst nodes per fuse block
#define FUSE_BLOCKS 1563  // ceil(N / NPB)

typedef __attribute__((ext_vector_type(8))) short bf16x8;   // 8 bf16 in 4 VGPRs
typedef __attribute__((ext_vector_type(4))) float f32x4;

static __host__ __device__ inline size_t align256(size_t x) { return (x + 255) & ~(size_t)255; }

__device__ inline unsigned short f2b(float f) {   // fp32 -> bf16 RNE
    unsigned u = __builtin_bit_cast(unsigned, f);
    unsigned r = (u + 0x7fffu + ((u >> 16) & 1u)) >> 16;
    return (unsigned short)r;
}
__device__ inline float b2f(unsigned short u) {   // bf16 -> fp32
    unsigned v = ((unsigned)u) << 16;
    return __builtin_bit_cast(float, v);
}

// ---------------------------------------------------------------------------
// Kernel 1: bucket fill, fixed-capacity regions. Entry = src|et<<16|dlo<<19.
// dst/src/et loaded as int4 (4 edges per load triple; E % 4 == 0).
// Rider: blocks 0..31 also build WtT[r][f][d] = bf16(W[r][d][f]) (64 KB).
// ---------------------------------------------------------------------------
__global__ void bfill_kernel(const int* __restrict__ dst, const int* __restrict__ srcv,
                             const int* __restrict__ et, const float* __restrict__ W,
                             int* __restrict__ bcnt, int* __restrict__ tmp,
                             unsigned short* __restrict__ WtT, int E) {
    __shared__ int hist[256];
    __shared__ int base[256];
    __shared__ int lcur[256];
    const int t = threadIdx.x;
    hist[t] = 0; lcur[t] = 0;
    __syncthreads();

    const int4* dst4 = (const int4*)dst;
    const int4* src4 = (const int4*)srcv;
    const int4* et4  = (const int4*)et;
    const int n4 = E >> 2;                    // E % 4 == 0
    int bk[8], pk[8];
#pragma unroll
    for (int k = 0; k < 2; k++) {
        int i4 = blockIdx.x * 512 + t + k * 256;
        if (i4 < n4) {
            int4 d = dst4[i4];
            int4 s = src4[i4];
            int4 r = et4[i4];
            const int dd[4] = {d.x, d.y, d.z, d.w};
            const int ss[4] = {s.x, s.y, s.z, s.w};
            const int rr[4] = {r.x, r.y, r.z, r.w};
#pragma unroll
            for (int j = 0; j < 4; j++) {
                int idx = k * 4 + j;
                bk[idx] = dd[j] >> 8;
                pk[idx] = (ss[j] & 0xFFFF) | (rr[j] << 16) | ((dd[j] & 255) << 19);
                atomicAdd(&hist[bk[idx]], 1);
            }
        } else {
#pragma unroll
            for (int j = 0; j < 4; j++) bk[k * 4 + j] = -1;
        }
    }
    __syncthreads();
    if (t < NBUCK && hist[t] > 0)
        base[t] = t * BCAP + atomicAdd(&bcnt[t], hist[t]);
    __syncthreads();
#pragma unroll
    for (int k = 0; k < 8; k++) {
        if (bk[k] >= 0) {
            int r = atomicAdd(&lcur[bk[k]], 1);
            int pos = base[bk[k]] + r;
            if (pos < (bk[k] + 1) * BCAP)   // memory-safety clamp (never hit)
                tmp[pos] = pk[k];
        }
    }

    // W transpose rider.
    if (blockIdx.x < 32) {
        int i4 = blockIdx.x * 256 + t;        // [0, 8192) float4s of W
        float4 v = ((const float4*)W)[i4];
        int bse = i4 * 4;                     // flat element = (r*64+d)*64 + f
        int f0 = bse & 63;
        int rd = bse >> 6;                    // r*64 + d
        int d  = rd & 63;
        int r  = rd >> 6;
        unsigned short* w0 = WtT + ((size_t)(r * 64 + f0) * 64 + d);
        w0[0 * 64] = f2b(v.x);
        w0[1 * 64] = f2b(v.y);
        w0[2 * 64] = f2b(v.z);
        w0[3 * 64] = f2b(v.w);
    }
}

// ---------------------------------------------------------------------------
// Kernel 2 (FUSED): blocks [0,NBUCK) = per-bucket sort + offsets;
// blocks [NBUCK, NBUCK+FB_BLOCKS) = feat -> bf16 conversion (Fb).
// (hwb transform removed: the transform now happens AFTER the reduce.)
// ---------------------------------------------------------------------------
__global__ void mid_kernel(const int* __restrict__ bcnt, const int* __restrict__ tmp,
                           int* __restrict__ spk, int* __restrict__ off_s,
                           int* __restrict__ off_e,
                           const float* __restrict__ feat,
                           unsigned short* __restrict__ Fb, int N) {
    __shared__ int s[256];
    __shared__ int cur[256];
    const int t = threadIdx.x;

    if (blockIdx.x < NBUCK) {
        // ------------------- sort3 half -------------------
        const int b = blockIdx.x;
        const int n0 = b * 256;
        const int nn = min(256, N - n0);
        const int s0 = b * BCAP;
        const int s1 = s0 + min(bcnt[b], BCAP);

        s[t] = 0;
        __syncthreads();
        for (int i = s0 + t; i < s1; i += 256)
            atomicAdd(&s[(tmp[i] >> 19) & 255], 1);
        __syncthreads();
        const int myc = s[t];
        for (int o = 1; o < 256; o <<= 1) {
            int u = (t >= o) ? s[t - o] : 0;
            __syncthreads();
            s[t] += u;
            __syncthreads();
        }
        const int ex = s0 + s[t] - myc;
        if (t < nn) {
            off_s[n0 + t] = ex;
            off_e[n0 + t] = ex + myc;
            cur[t] = ex;
        }
        __syncthreads();
        for (int i = s0 + t; i < s1; i += 256) {
            int e = tmp[i];
            int pos = atomicAdd(&cur[(e >> 19) & 255], 1);
            spk[pos] = e;
        }
        return;
    }

    // ------------------- Fb half: bf16(feat) -------------------
    const int fbb = blockIdx.x - NBUCK;
    const int node = fbb * 64 + (t >> 2);
    if (node >= N) return;
    const int seg = t & 3;
    const float4* F4 = (const float4*)feat + (size_t)node * 16 + seg * 4;
    float4 v0 = F4[0], v1 = F4[1], v2 = F4[2], v3 = F4[3];
    bf16x8 b0, b1;
    b0[0] = (short)f2b(v0.x); b0[1] = (short)f2b(v0.y);
    b0[2] = (short)f2b(v0.z); b0[3] = (short)f2b(v0.w);
    b0[4] = (short)f2b(v1.x); b0[5] = (short)f2b(v1.y);
    b0[6] = (short)f2b(v1.z); b0[7] = (short)f2b(v1.w);
    b1[0] = (short)f2b(v2.x); b1[1] = (short)f2b(v2.y);
    b1[2] = (short)f2b(v2.z); b1[3] = (short)f2b(v2.w);
    b1[4] = (short)f2b(v3.x); b1[5] = (short)f2b(v3.y);
    b1[6] = (short)f2b(v3.z); b1[7] = (short)f2b(v3.w);
    *(bf16x8*)(Fb + (size_t)node * 64 + seg * 16)     = b0;
    *(bf16x8*)(Fb + (size_t)node * 64 + seg * 16 + 8) = b1;
}

// ---------------------------------------------------------------------------
// Kernel 3 (NEW): fused gather-sum -> per-relation MFMA -> epilogue.
// M[v] = sum_r ( sum_{e into v, rel r} h_bf16[src_e] ) @ W_r
// 32 dst nodes / block. S[8][32][64] f32 in LDS (64 KB, XOR-swizzled d-blocks).
// One 8-lane group owns one node: plain LDS RMW, no atomics, prefetch-1 edge.
// ---------------------------------------------------------------------------
__global__ __launch_bounds__(256, 2) void fuse_kernel(
    const int* __restrict__ off_s, const int* __restrict__ off_e,
    const int* __restrict__ spk, const unsigned short* __restrict__ Fb,
    const unsigned short* __restrict__ WtT, const float* __restrict__ feat,
    float* __restrict__ out, int N) {
    __shared__ float SL[NRELS * NPB * 64];   // 65536 B
    const int t = threadIdx.x;
    const int n0 = blockIdx.x * NPB;
    const int nn = min(NPB, N - n0);
    const int w = t >> 6, l = t & 63, col = l & 15, quad = l >> 4;

    // Hoisted B fragments: wave w owns f-tile [w*16, w*16+16).
    // Lane holds WtT row f = w*16+col, d = quad*8 + {0..7} (bw0) / {32..39} (bw1).
    bf16x8 bw0[NRELS], bw1[NRELS];
#pragma unroll
    for (int r = 0; r < NRELS; r++) {
        const unsigned short* wp = WtT + (size_t)r * 4096 + ((w * 16 + col) * 64 + quad * 8);
        bw0[r] = *(const bf16x8*)wp;
        bw1[r] = *(const bf16x8*)(wp + 32);
    }

    // Zero S.
    {
        f32x4 z = {0.f, 0.f, 0.f, 0.f};
#pragma unroll
        for (int i = 0; i < 16; i++)
            *(f32x4*)&SL[(i * 256 + t) * 4] = z;
    }
    __syncthreads();

    // Gather + accumulate: group gid (8 lanes) owns node n0+gid.
    // d-block swizzle: block (d>>3) stored at (d>>3) ^ (n&7)  -> <=2-way banks.
    const int gid = t >> 3, q = t & 7;
    if (gid < nn) {
        const int gn = n0 + gid;
        const int rowbase = gid * 64 + 8 * (q ^ (gid & 7));
        const int b = off_s[gn], e = off_e[gn];
        if (b < e) {
            int pk = spk[b];
            bf16x8 u = *(const bf16x8*)(Fb + (size_t)(pk & 0xFFFF) * 64 + q * 8);
            for (int i = b; i < e; i++) {
                int pk_n = 0;
                bf16x8 u_n = u;
                if (i + 1 < e) {    // prefetch next edge (hides L2 latency under RMW)
                    pk_n = spk[i + 1];
                    u_n = *(const bf16x8*)(Fb + (size_t)(pk_n & 0xFFFF) * 64 + q * 8);
                }
                const int r = (pk >> 16) & 7;
                float* p = &SL[r * (NPB * 64) + rowbase];
                float4 x0 = *(float4*)p;
                float4 x1 = *(float4*)(p + 4);
                x0.x += b2f((unsigned short)u[0]);
                x0.y += b2f((unsigned short)u[1]);
                x0.z += b2f((unsigned short)u[2]);
                x0.w += b2f((unsigned short)u[3]);
                x1.x += b2f((unsigned short)u[4]);
                x1.y += b2f((unsigned short)u[5]);
                x1.z += b2f((unsigned short)u[6]);
                x1.w += b2f((unsigned short)u[7]);
                *(float4*)p = x0;
                *(float4*)(p + 4) = x1;
                pk = pk_n; u = u_n;
            }
        }
    }
    __syncthreads();

    // MFMA: C[n][f] = sum_r S_r[n][:] @ W_r[:][f], K=64 per rel (2 MFMAs).
    f32x4 acc0 = {0.f, 0.f, 0.f, 0.f}, acc1 = {0.f, 0.f, 0.f, 0.f};
    const int o0 = 8 * (quad ^ (col & 7));          // (16+col)&7 == col&7
    const int o1 = 8 * ((quad + 4) ^ (col & 7));
#pragma unroll
    for (int r = 0; r < NRELS; r++) {
        const float* Sr = &SL[r * (NPB * 64)];
        {   // M-tile 0: nodes 0..15  (A-row = col)
            const float* ap = Sr + col * 64;
            float4 fa = *(const float4*)(ap + o0);
            float4 fb = *(const float4*)(ap + o0 + 4);
            float4 fc = *(const float4*)(ap + o1);
            float4 fd = *(const float4*)(ap + o1 + 4);
            bf16x8 a0, a1;
            a0[0] = (short)f2b(fa.x); a0[1] = (short)f2b(fa.y);
            a0[2] = (short)f2b(fa.z); a0[3] = (short)f2b(fa.w);
            a0[4] = (short)f2b(fb.x); a0[5] = (short)f2b(fb.y);
            a0[6] = (short)f2b(fb.z); a0[7] = (short)f2b(fb.w);
            a1[0] = (short)f2b(fc.x); a1[1] = (short)f2b(fc.y);
            a1[2] = (short)f2b(fc.z); a1[3] = (short)f2b(fc.w);
            a1[4] = (short)f2b(fd.x); a1[5] = (short)f2b(fd.y);
            a1[6] = (short)f2b(fd.z); a1[7] = (short)f2b(fd.w);
            acc0 = __builtin_amdgcn_mfma_f32_16x16x32_bf16(a0, bw0[r], acc0, 0, 0, 0);
            acc0 = __builtin_amdgcn_mfma_f32_16x16x32_bf16(a1, bw1[r], acc0, 0, 0, 0);
        }
        {   // M-tile 1: nodes 16..31
            const float* ap = Sr + (16 + col) * 64;
            float4 fa = *(const float4*)(ap + o0);
            float4 fb = *(const float4*)(ap + o0 + 4);
            float4 fc = *(const float4*)(ap + o1);
            float4 fd = *(const float4*)(ap + o1 + 4);
            bf16x8 a0, a1;
            a0[0] = (short)f2b(fa.x); a0[1] = (short)f2b(fa.y);
            a0[2] = (short)f2b(fa.z); a0[3] = (short)f2b(fa.w);
            a0[4] = (short)f2b(fb.x); a0[5] = (short)f2b(fb.y);
            a0[6] = (short)f2b(fb.z); a0[7] = (short)f2b(fb.w);
            a1[0] = (short)f2b(fc.x); a1[1] = (short)f2b(fc.y);
            a1[2] = (short)f2b(fc.z); a1[3] = (short)f2b(fc.w);
            a1[4] = (short)f2b(fd.x); a1[5] = (short)f2b(fd.y);
            a1[6] = (short)f2b(fd.z); a1[7] = (short)f2b(fd.w);
            acc1 = __builtin_amdgcn_mfma_f32_16x16x32_bf16(a0, bw0[r], acc1, 0, 0, 0);
            acc1 = __builtin_amdgcn_mfma_f32_16x16x32_bf16(a1, bw1[r], acc1, 0, 0, 0);
        }
    }
    __syncthreads();   // all S reads done -> SL reusable as C bounce [32][64] f32

    // C fragment layout: col = lane&15 (f within tile), row = quad*4 + i (node).
#pragma unroll
    for (int i = 0; i < 4; i++) {
        SL[(quad * 4 + i) * 64 + w * 16 + col]        = acc0[i];
        SL[(16 + quad * 4 + i) * 64 + w * 16 + col]   = acc1[i];
    }
    __syncthreads();

    // Epilogue: coalesced. Thread handles 8 floats of node n = t>>3.
    {
        const int n = t >> 3;
        if (n < nn) {
            const int gn = n0 + n;
            const int f0 = (t & 7) * 8;
            const int deg = off_e[gn] - off_s[gn];
            float4 m0 = *(const float4*)&SL[n * 64 + f0];
            float4 m1 = *(const float4*)&SL[n * 64 + f0 + 4];
            const float4* fp = (const float4*)feat + (size_t)gn * 16 + (f0 >> 2);
            float4 h0 = fp[0], h1 = fp[1];
            float4 r0, r1;
            if (deg > 0) {
                float inv = 0.8f / (float)deg;
                r0.x = fmaxf(0.2f * h0.x + m0.x * inv, 0.f);
                r0.y = fmaxf(0.2f * h0.y + m0.y * inv, 0.f);
                r0.z = fmaxf(0.2f * h0.z + m0.z * inv, 0.f);
                r0.w = fmaxf(0.2f * h0.w + m0.w * inv, 0.f);
                r1.x = fmaxf(0.2f * h1.x + m1.x * inv, 0.f);
                r1.y = fmaxf(0.2f * h1.y + m1.y * inv, 0.f);
                r1.z = fmaxf(0.2f * h1.z + m1.z * inv, 0.f);
                r1.w = fmaxf(0.2f * h1.w + m1.w * inv, 0.f);
            } else {
                r0 = h0; r1 = h1;
            }
            float4* op = (float4*)out + (size_t)gn * 16 + (f0 >> 2);
            op[0] = r0;
            op[1] = r1;
        }
    }
}

// ---------------------------------------------------------------------------
// Fallback kernels (small workspace): on-the-fly transform + atomics (fp32).
// ---------------------------------------------------------------------------
__global__ void degf_kernel(const int* __restrict__ dst, float* __restrict__ deg, int E) {
    int e = blockIdx.x * blockDim.x + threadIdx.x;
    if (e < E) atomicAdd(deg + dst[e], 1.0f);
}

__global__ void otf_kernel(const int* __restrict__ src, const int* __restrict__ dst,
                           const int* __restrict__ et, const float* __restrict__ feat,
                           const float* __restrict__ W, float* __restrict__ out, int E) {
    int wid = (blockIdx.x * blockDim.x + threadIdx.x) >> 6;
    int l = threadIdx.x & 63;
    if (wid >= E) return;
    int s = src[wid], dd = dst[wid], r = et[wid];
    float fv = feat[(size_t)s * 64 + l];
    const float* Wr = W + (size_t)r * 4096;
    float acc = 0.f;
#pragma unroll
    for (int d = 0; d < 64; d++) {
        float a = __shfl(fv, d);
        acc += a * Wr[d * 64 + l];
    }
    atomicAdd(out + (size_t)dd * 64 + l, acc);
}

__global__ void final_kernel(const float* __restrict__ feat, const float* __restrict__ deg,
                             float* __restrict__ out, int N) {
    int i = blockIdx.x * blockDim.x + threadIdx.x;
    if (i >= N * 16) return;
    int n = i >> 4;
    float d = deg[n];
    float4 f = ((const float4*)feat)[i];
    float4 m = ((float4*)out)[i];
    float4 res;
    if (d > 0.f) {
        float inv = 0.8f / d;
        res.x = fmaxf(0.2f * f.x + m.x * inv, 0.f);
        res.y = fmaxf(0.2f * f.y + m.y * inv, 0.f);
        res.z = fmaxf(0.2f * f.z + m.z * inv, 0.f);
        res.w = fmaxf(0.2f * f.w + m.w * inv, 0.f);
    } else {
        res = f;
    }
    ((float4*)out)[i] = res;
}

extern "C" void kernel_launch(void* const* d_in, const int* in_sizes, int n_in,
                              void* d_out, int out_size, void* d_ws, size_t ws_size,
                              hipStream_t stream) {
    const float* feat = (const float*)d_in[0];   // [N, 64]
    const float* W    = (const float*)d_in[1];   // [8, 64, 64]
    const int*   src  = (const int*)d_in[2];     // [E]
    const int*   dst  = (const int*)d_in[3];     // [E]
    const int*   et   = (const int*)d_in[4];     // [E]
    float* out = (float*)d_out;                  // [N, 64]

    const int N = N_NODES, E = N_EDGES;

    // Workspace layout:
    char* p = (char*)d_ws;
    int* bcnt  = (int*)p;  p += align256((size_t)NBUCK * 4);
    int* off_s = (int*)p;  p += align256((size_t)N * 4);
    int* off_e = (int*)p;  p += align256((size_t)N * 4);
    int* tmp   = (int*)p;  p += align256((size_t)NBUCK * BCAP * 4);   // 4.0 MB
    int* spk   = (int*)p;  p += align256((size_t)NBUCK * BCAP * 4);   // 4.0 MB
    unsigned short* WtT = (unsigned short*)p;
    p += align256((size_t)NRELS * FEAT * FEAT * 2);                   // 64 KB
    unsigned short* Fb = (unsigned short*)p;
    p += align256((size_t)N * FEAT * 2);                              // 6.4 MB
    size_t need_full = (size_t)(p - (char*)d_ws);

    if (ws_size >= need_full) {
        hipMemsetAsync(bcnt, 0, (size_t)NBUCK * 4, stream);
        bfill_kernel<<<NBP, 256, 0, stream>>>(dst, src, et, W, bcnt, tmp, WtT, E);
        mid_kernel<<<NBUCK + FB_BLOCKS, 256, 0, stream>>>(bcnt, tmp, spk, off_s, off_e,
                                                          feat, Fb, N);
        fuse_kernel<<<FUSE_BLOCKS, 256, 0, stream>>>(off_s, off_e, spk, Fb, WtT,
                                                     feat, out, N);
    } else {
        // Minimal-workspace fallback.
        float* deg = (float*)d_ws;
        hipMemsetAsync(out, 0, (size_t)N * FEAT * 4, stream);
        hipMemsetAsync(deg, 0, (size_t)N * 4, stream);
        degf_kernel<<<(E + 255) / 256, 256, 0, stream>>>(dst, deg, E);
        otf_kernel<<<(E + 3) / 4, 256, 0, stream>>>(src, dst, et, feat, W, out, E);
        final_kernel<<<(N * 16 + 255) / 256, 256, 0, stream>>>(feat, deg, out, N);
    }
}

// Round 3
// 142.061 us; speedup vs baseline: 1.2704x; 1.2704x over previous
//
#include <hip/hip_runtime.h>
#include <hip/hip_bf16.h>

#define N_NODES 50000
#define N_EDGES 800000
#define FEAT 64
#define NRELS 8
#define NBUCK 196         // ceil(50000/256) buckets of 256 dst nodes (dst >> 8)
#define EPB 2048          // edges per bfill block
#define NBP 391           // ceil(E / EPB)
#define BCAP 5120         // fixed slots per bucket (mean 4082 + 16 sigma)
#define FB_BLOCKS 782     // ceil(N / 64) feat->bf16 rider blocks in mid
#define NPB 32            // dst nodes per fuse block
#define FUSE_BLOCKS 1563  // ceil(N / NPB)

typedef __attribute__((ext_vector_type(8))) short bf16x8;   // 8 bf16 in 4 VGPRs
typedef __attribute__((ext_vector_type(4))) float f32x4;

static __host__ __device__ inline size_t align256(size_t x) { return (x + 255) & ~(size_t)255; }

__device__ inline unsigned short f2b(float f) {   // fp32 -> bf16 RNE
    unsigned u = __builtin_bit_cast(unsigned, f);
    unsigned r = (u + 0x7fffu + ((u >> 16) & 1u)) >> 16;
    return (unsigned short)r;
}
__device__ inline float b2f(unsigned short u) {   // bf16 -> fp32
    unsigned v = ((unsigned)u) << 16;
    return __builtin_bit_cast(float, v);
}

// ---------------------------------------------------------------------------
// Kernel 1: bucket fill, fixed-capacity regions. Entry = src|et<<16|dlo<<19.
// dst/src/et loaded as int4 (4 edges per load triple; E % 4 == 0).
// Rider: blocks 0..31 also build WtT[r][f][d] = bf16(W[r][d][f]) (64 KB).
// ---------------------------------------------------------------------------
__global__ void bfill_kernel(const int* __restrict__ dst, const int* __restrict__ srcv,
                             const int* __restrict__ et, const float* __restrict__ W,
                             int* __restrict__ bcnt, int* __restrict__ tmp,
                             unsigned short* __restrict__ WtT, int E) {
    __shared__ int hist[256];
    __shared__ int base[256];
    __shared__ int lcur[256];
    const int t = threadIdx.x;
    hist[t] = 0; lcur[t] = 0;
    __syncthreads();

    const int4* dst4 = (const int4*)dst;
    const int4* src4 = (const int4*)srcv;
    const int4* et4  = (const int4*)et;
    const int n4 = E >> 2;                    // E % 4 == 0
    int bk[8], pk[8];
#pragma unroll
    for (int k = 0; k < 2; k++) {
        int i4 = blockIdx.x * 512 + t + k * 256;
        if (i4 < n4) {
            int4 d = dst4[i4];
            int4 s = src4[i4];
            int4 r = et4[i4];
            const int dd[4] = {d.x, d.y, d.z, d.w};
            const int ss[4] = {s.x, s.y, s.z, s.w};
            const int rr[4] = {r.x, r.y, r.z, r.w};
#pragma unroll
            for (int j = 0; j < 4; j++) {
                int idx = k * 4 + j;
                bk[idx] = dd[j] >> 8;
                pk[idx] = (ss[j] & 0xFFFF) | (rr[j] << 16) | ((dd[j] & 255) << 19);
                atomicAdd(&hist[bk[idx]], 1);
            }
        } else {
#pragma unroll
            for (int j = 0; j < 4; j++) bk[k * 4 + j] = -1;
        }
    }
    __syncthreads();
    if (t < NBUCK && hist[t] > 0)
        base[t] = t * BCAP + atomicAdd(&bcnt[t], hist[t]);
    __syncthreads();
#pragma unroll
    for (int k = 0; k < 8; k++) {
        if (bk[k] >= 0) {
            int r = atomicAdd(&lcur[bk[k]], 1);
            int pos = base[bk[k]] + r;
            if (pos < (bk[k] + 1) * BCAP)   // memory-safety clamp (never hit)
                tmp[pos] = pk[k];
        }
    }

    // W transpose rider.
    if (blockIdx.x < 32) {
        int i4 = blockIdx.x * 256 + t;        // [0, 8192) float4s of W
        float4 v = ((const float4*)W)[i4];
        int bse = i4 * 4;                     // flat element = (r*64+d)*64 + f
        int f0 = bse & 63;
        int rd = bse >> 6;                    // r*64 + d
        int d  = rd & 63;
        int r  = rd >> 6;
        unsigned short* w0 = WtT + ((size_t)(r * 64 + f0) * 64 + d);
        w0[0 * 64] = f2b(v.x);
        w0[1 * 64] = f2b(v.y);
        w0[2 * 64] = f2b(v.z);
        w0[3 * 64] = f2b(v.w);
    }
}

// ---------------------------------------------------------------------------
// Kernel 2 (FUSED): blocks [0,NBUCK) = per-bucket counting sort by
// bin = dlo*8 + rel (2048 bins) -> edges of a node are rel-contiguous;
// blocks [NBUCK, NBUCK+FB_BLOCKS) = feat -> bf16 conversion (Fb).
// ---------------------------------------------------------------------------
__global__ void mid_kernel(const int* __restrict__ bcnt, const int* __restrict__ tmp,
                           int* __restrict__ spk, int* __restrict__ off_s,
                           int* __restrict__ off_e,
                           const float* __restrict__ feat,
                           unsigned short* __restrict__ Fb, int N) {
    __shared__ int hist[2048];
    __shared__ int s[256];
    const int t = threadIdx.x;

    if (blockIdx.x < NBUCK) {
        // ------------------- sort half (2048-bin) -------------------
        const int b = blockIdx.x;
        const int n0 = b * 256;
        const int nn = min(256, N - n0);
        const int s0 = b * BCAP;
        const int s1 = s0 + min(bcnt[b], BCAP);

#pragma unroll
        for (int j = 0; j < 8; j++) hist[t * 8 + j] = 0;
        __syncthreads();
        // count pass, 4x unrolled for MLP
        for (int i = s0 + t; i < s1; i += 1024) {
            int v0 = tmp[i];
            int v1 = (i + 256 < s1) ? tmp[i + 256] : -1;
            int v2 = (i + 512 < s1) ? tmp[i + 512] : -1;
            int v3 = (i + 768 < s1) ? tmp[i + 768] : -1;
            atomicAdd(&hist[(v0 >> 16) & 0x7FF], 1);
            if (v1 >= 0) atomicAdd(&hist[(v1 >> 16) & 0x7FF], 1);
            if (v2 >= 0) atomicAdd(&hist[(v2 >> 16) & 0x7FF], 1);
            if (v3 >= 0) atomicAdd(&hist[(v3 >> 16) & 0x7FF], 1);
        }
        __syncthreads();
        // two-level scan: thread t owns bins [t*8, t*8+8) = node t's 8 rels
        int loc[8], st[8], T = 0;
#pragma unroll
        for (int j = 0; j < 8; j++) loc[j] = hist[t * 8 + j];
#pragma unroll
        for (int j = 0; j < 8; j++) { st[j] = T; T += loc[j]; }
        s[t] = T;
        __syncthreads();
        for (int o = 1; o < 256; o <<= 1) {
            int u = (t >= o) ? s[t - o] : 0;
            __syncthreads();
            s[t] += u;
            __syncthreads();
        }
        const int base = s0 + s[t] - T;       // exclusive over threads
        if (t < nn) {
            off_s[n0 + t] = base;
            off_e[n0 + t] = base + T;
        }
#pragma unroll
        for (int j = 0; j < 8; j++) hist[t * 8 + j] = base + st[j];
        __syncthreads();
        // scatter pass, 4x unrolled
        for (int i = s0 + t; i < s1; i += 1024) {
            int v0 = tmp[i];
            int v1 = (i + 256 < s1) ? tmp[i + 256] : -1;
            int v2 = (i + 512 < s1) ? tmp[i + 512] : -1;
            int v3 = (i + 768 < s1) ? tmp[i + 768] : -1;
            int p0 = atomicAdd(&hist[(v0 >> 16) & 0x7FF], 1);
            spk[p0] = v0;
            if (v1 >= 0) { int p1 = atomicAdd(&hist[(v1 >> 16) & 0x7FF], 1); spk[p1] = v1; }
            if (v2 >= 0) { int p2 = atomicAdd(&hist[(v2 >> 16) & 0x7FF], 1); spk[p2] = v2; }
            if (v3 >= 0) { int p3 = atomicAdd(&hist[(v3 >> 16) & 0x7FF], 1); spk[p3] = v3; }
        }
        return;
    }

    // ------------------- Fb half: bf16(feat) -------------------
    const int fbb = blockIdx.x - NBUCK;
    const int node = fbb * 64 + (t >> 2);
    if (node >= N) return;
    const int seg = t & 3;
    const float4* F4 = (const float4*)feat + (size_t)node * 16 + seg * 4;
    float4 v0 = F4[0], v1 = F4[1], v2 = F4[2], v3 = F4[3];
    bf16x8 b0, b1;
    b0[0] = (short)f2b(v0.x); b0[1] = (short)f2b(v0.y);
    b0[2] = (short)f2b(v0.z); b0[3] = (short)f2b(v0.w);
    b0[4] = (short)f2b(v1.x); b0[5] = (short)f2b(v1.y);
    b0[6] = (short)f2b(v1.z); b0[7] = (short)f2b(v1.w);
    b1[0] = (short)f2b(v2.x); b1[1] = (short)f2b(v2.y);
    b1[2] = (short)f2b(v2.z); b1[3] = (short)f2b(v2.w);
    b1[4] = (short)f2b(v3.x); b1[5] = (short)f2b(v3.y);
    b1[6] = (short)f2b(v3.z); b1[7] = (short)f2b(v3.w);
    *(bf16x8*)(Fb + (size_t)node * 64 + seg * 16)     = b0;
    *(bf16x8*)(Fb + (size_t)node * 64 + seg * 16 + 8) = b1;
}

// ---------------------------------------------------------------------------
// Kernel 3: fused gather-sum -> per-relation MFMA -> epilogue.
// Edges sorted by (node, rel): 8-lane group register-accumulates each
// (node,rel) segment, flushes ONCE to bf16 S in LDS (write-only, swizzled).
// S bf16 [8][32][64] = 32 KB -> 4 blocks/CU. 4-deep edge prefetch.
// ---------------------------------------------------------------------------
__global__ __launch_bounds__(256, 4) void fuse_kernel(
    const int* __restrict__ off_s, const int* __restrict__ off_e,
    const int* __restrict__ spk, const unsigned short* __restrict__ Fb,
    const unsigned short* __restrict__ WtT, const float* __restrict__ feat,
    float* __restrict__ out, int N) {
    __shared__ unsigned short Sb[NRELS][NPB][64];   // 32768 B, swizzled d-blocks
    const int t = threadIdx.x;
    const int n0 = blockIdx.x * NPB;
    const int nn = min(NPB, N - n0);

    // Zero S (covers nodes/rels with no edges).
    {
        f32x4 z = {0.f, 0.f, 0.f, 0.f};
        f32x4* zp = (f32x4*)&Sb[0][0][0];
#pragma unroll
        for (int i = 0; i < 8; i++) zp[t + 256 * i] = z;
    }
    __syncthreads();

    // ---- gather: group gid (8 lanes) owns node n0+gid; lane q owns d-block q.
    const int gid = t >> 3, q = t & 7;
    if (gid < nn) {
        const int gn = n0 + gid;
        const int b = off_s[gn], e = off_e[gn];
        const int swz = (q ^ (gid & 7)) * 8;          // physical slot of logical block q
        unsigned short* srow = &Sb[0][0][0] + (size_t)gid * 64 + swz;
        float a[8] = {0.f, 0.f, 0.f, 0.f, 0.f, 0.f, 0.f, 0.f};
        int curR = -1;

        auto flushS = [&](int rel) {
            bf16x8 v;
#pragma unroll
            for (int k = 0; k < 8; k++) v[k] = (short)f2b(a[k]);
            *(bf16x8*)(srow + (size_t)rel * (NPB * 64)) = v;
        };
        auto proc = [&](int pk, bf16x8 u) {
            if (pk < 0) return;
            int r_ = (pk >> 16) & 7;
            if (r_ != curR) {
                if (curR >= 0) flushS(curR);
                curR = r_;
#pragma unroll
                for (int k = 0; k < 8; k++) a[k] = b2f((unsigned short)u[k]);
            } else {
#pragma unroll
                for (int k = 0; k < 8; k++) a[k] += b2f((unsigned short)u[k]);
            }
        };
        auto ld = [&](int idx, int& pk, bf16x8& u) {
            if (idx < e) {
                pk = spk[idx];
                u = *(const bf16x8*)(Fb + (size_t)(pk & 0xFFFF) * 64 + q * 8);
            } else {
                pk = -1;
                u = (bf16x8){0, 0, 0, 0, 0, 0, 0, 0};
            }
        };

        int pk0, pk1, pk2, pk3;
        bf16x8 u0 = {0,0,0,0,0,0,0,0}, u1 = u0, u2 = u0, u3 = u0;
        ld(b, pk0, u0); ld(b + 1, pk1, u1); ld(b + 2, pk2, u2); ld(b + 3, pk3, u3);
        for (int i = b; i < e; i += 4) {
            int np0, np1, np2, np3;
            bf16x8 v0 = u0, v1 = u0, v2 = u0, v3 = u0;
            ld(i + 4, np0, v0); ld(i + 5, np1, v1);
            ld(i + 6, np2, v2); ld(i + 7, np3, v3);
            proc(pk0, u0); proc(pk1, u1); proc(pk2, u2); proc(pk3, u3);
            pk0 = np0; u0 = v0; pk1 = np1; u1 = v1;
            pk2 = np2; u2 = v2; pk3 = np3; u3 = v3;
        }
        if (curR >= 0) flushS(curR);
    }
    __syncthreads();

    // ---- MFMA: C[n][f] = sum_r S_r[n][:] @ W_r[:][f]. S is bf16: no f2b here.
    const int w = t >> 6, l = t & 63, col = l & 15, quad = l >> 4;
    f32x4 acc0 = {0.f, 0.f, 0.f, 0.f}, acc1 = {0.f, 0.f, 0.f, 0.f};
    const int sw0 = (quad ^ (col & 7)) * 8;           // logical k-block quad
    const int sw1 = ((quad + 4) ^ (col & 7)) * 8;     // logical k-block quad+4
#pragma unroll
    for (int r = 0; r < NRELS; r++) {
        const unsigned short* wp = WtT + (size_t)r * 4096 + ((w * 16 + col) * 64 + quad * 8);
        bf16x8 b0 = *(const bf16x8*)wp;               // W frags from L2 (hot)
        bf16x8 b1 = *(const bf16x8*)(wp + 32);
        const unsigned short* Sr = &Sb[0][0][0] + (size_t)r * (NPB * 64);
        bf16x8 a0 = *(const bf16x8*)&Sr[col * 64 + sw0];
        bf16x8 a1 = *(const bf16x8*)&Sr[col * 64 + sw1];
        bf16x8 c0 = *(const bf16x8*)&Sr[(16 + col) * 64 + sw0];
        bf16x8 c1 = *(const bf16x8*)&Sr[(16 + col) * 64 + sw1];
        acc0 = __builtin_amdgcn_mfma_f32_16x16x32_bf16(a0, b0, acc0, 0, 0, 0);
        acc0 = __builtin_amdgcn_mfma_f32_16x16x32_bf16(a1, b1, acc0, 0, 0, 0);
        acc1 = __builtin_amdgcn_mfma_f32_16x16x32_bf16(c0, b0, acc1, 0, 0, 0);
        acc1 = __builtin_amdgcn_mfma_f32_16x16x32_bf16(c1, b1, acc1, 0, 0, 0);
    }
    __syncthreads();   // all S reads done -> alias Sb as C bounce [32][72] f32

    float* C = (float*)&Sb[0][0][0];
#pragma unroll
    for (int i = 0; i < 4; i++) {
        C[(quad * 4 + i) * 72 + w * 16 + col]        = acc0[i];
        C[(16 + quad * 4 + i) * 72 + w * 16 + col]   = acc1[i];
    }
    __syncthreads();

    // ---- epilogue: thread t -> node t>>3, f-block t&7 (coalesced).
    {
        const int n = t >> 3;
        if (n < nn) {
            const int gn = n0 + n;
            const int f0 = (t & 7) * 8;
            const int deg = off_e[gn] - off_s[gn];
            float4 m0 = *(const float4*)&C[n * 72 + f0];
            float4 m1 = *(const float4*)&C[n * 72 + f0 + 4];
            const float4* fp = (const float4*)feat + (size_t)gn * 16 + (f0 >> 2);
            float4 h0 = fp[0], h1 = fp[1];
            float4 r0, r1;
            if (deg > 0) {
                float inv = 0.8f / (float)deg;
                r0.x = fmaxf(0.2f * h0.x + m0.x * inv, 0.f);
                r0.y = fmaxf(0.2f * h0.y + m0.y * inv, 0.f);
                r0.z = fmaxf(0.2f * h0.z + m0.z * inv, 0.f);
                r0.w = fmaxf(0.2f * h0.w + m0.w * inv, 0.f);
                r1.x = fmaxf(0.2f * h1.x + m1.x * inv, 0.f);
                r1.y = fmaxf(0.2f * h1.y + m1.y * inv, 0.f);
                r1.z = fmaxf(0.2f * h1.z + m1.z * inv, 0.f);
                r1.w = fmaxf(0.2f * h1.w + m1.w * inv, 0.f);
            } else {
                r0 = h0; r1 = h1;
            }
            float4* op = (float4*)out + (size_t)gn * 16 + (f0 >> 2);
            op[0] = r0;
            op[1] = r1;
        }
    }
}

// ---------------------------------------------------------------------------
// Fallback kernels (small workspace): on-the-fly transform + atomics (fp32).
// ---------------------------------------------------------------------------
__global__ void degf_kernel(const int* __restrict__ dst, float* __restrict__ deg, int E) {
    int e = blockIdx.x * blockDim.x + threadIdx.x;
    if (e < E) atomicAdd(deg + dst[e], 1.0f);
}

__global__ void otf_kernel(const int* __restrict__ src, const int* __restrict__ dst,
                           const int* __restrict__ et, const float* __restrict__ feat,
                           const float* __restrict__ W, float* __restrict__ out, int E) {
    int wid = (blockIdx.x * blockDim.x + threadIdx.x) >> 6;
    int l = threadIdx.x & 63;
    if (wid >= E) return;
    int s = src[wid], dd = dst[wid], r = et[wid];
    float fv = feat[(size_t)s * 64 + l];
    const float* Wr = W + (size_t)r * 4096;
    float acc = 0.f;
#pragma unroll
    for (int d = 0; d < 64; d++) {
        float a = __shfl(fv, d);
        acc += a * Wr[d * 64 + l];
    }
    atomicAdd(out + (size_t)dd * 64 + l, acc);
}

__global__ void final_kernel(const float* __restrict__ feat, const float* __restrict__ deg,
                             float* __restrict__ out, int N) {
    int i = blockIdx.x * blockDim.x + threadIdx.x;
    if (i >= N * 16) return;
    int n = i >> 4;
    float d = deg[n];
    float4 f = ((const float4*)feat)[i];
    float4 m = ((float4*)out)[i];
    float4 res;
    if (d > 0.f) {
        float inv = 0.8f / d;
        res.x = fmaxf(0.2f * f.x + m.x * inv, 0.f);
        res.y = fmaxf(0.2f * f.y + m.y * inv, 0.f);
        res.z = fmaxf(0.2f * f.z + m.z * inv, 0.f);
        res.w = fmaxf(0.2f * f.w + m.w * inv, 0.f);
    } else {
        res = f;
    }
    ((float4*)out)[i] = res;
}

extern "C" void kernel_launch(void* const* d_in, const int* in_sizes, int n_in,
                              void* d_out, int out_size, void* d_ws, size_t ws_size,
                              hipStream_t stream) {
    const float* feat = (const float*)d_in[0];   // [N, 64]
    const float* W    = (const float*)d_in[1];   // [8, 64, 64]
    const int*   src  = (const int*)d_in[2];     // [E]
    const int*   dst  = (const int*)d_in[3];     // [E]
    const int*   et   = (const int*)d_in[4];     // [E]
    float* out = (float*)d_out;                  // [N, 64]

    const int N = N_NODES, E = N_EDGES;

    // Workspace layout:
    char* p = (char*)d_ws;
    int* bcnt  = (int*)p;  p += align256((size_t)NBUCK * 4);
    int* off_s = (int*)p;  p += align256((size_t)N * 4);
    int* off_e = (int*)p;  p += align256((size_t)N * 4);
    int* tmp   = (int*)p;  p += align256((size_t)NBUCK * BCAP * 4);   // 4.0 MB
    int* spk   = (int*)p;  p += align256((size_t)NBUCK * BCAP * 4);   // 4.0 MB
    unsigned short* WtT = (unsigned short*)p;
    p += align256((size_t)NRELS * FEAT * FEAT * 2);                   // 64 KB
    unsigned short* Fb = (unsigned short*)p;
    p += align256((size_t)N * FEAT * 2);                              // 6.4 MB
    size_t need_full = (size_t)(p - (char*)d_ws);

    if (ws_size >= need_full) {
        hipMemsetAsync(bcnt, 0, (size_t)NBUCK * 4, stream);
        bfill_kernel<<<NBP, 256, 0, stream>>>(dst, src, et, W, bcnt, tmp, WtT, E);
        mid_kernel<<<NBUCK + FB_BLOCKS, 256, 0, stream>>>(bcnt, tmp, spk, off_s, off_e,
                                                          feat, Fb, N);
        fuse_kernel<<<FUSE_BLOCKS, 256, 0, stream>>>(off_s, off_e, spk, Fb, WtT,
                                                     feat, out, N);
    } else {
        // Minimal-workspace fallback.
        float* deg = (float*)d_ws;
        hipMemsetAsync(out, 0, (size_t)N * FEAT * 4, stream);
        hipMemsetAsync(deg, 0, (size_t)N * 4, stream);
        degf_kernel<<<(E + 255) / 256, 256, 0, stream>>>(dst, deg, E);
        otf_kernel<<<(E + 3) / 4, 256, 0, stream>>>(src, dst, et, feat, W, out, E);
        final_kernel<<<(N * 16 + 255) / 256, 256, 0, stream>>>(feat, deg, out, N);
    }
}

// Round 4
// 123.372 us; speedup vs baseline: 1.4629x; 1.1515x over previous
//
#include <hip/hip_runtime.h>
#include <hip/hip_bf16.h>

#define N_NODES 50000
#define N_EDGES 800000
#define FEAT 64
#define NRELS 8
#define NBUCK 196         // ceil(50000/256) buckets of 256 dst nodes (dst >> 8)
#define EPB 4096          // edges per bfill block
#define NBP 196           // ceil(E / EPB)
#define BCAP 5120         // fixed slots per bucket (mean 4096 + 16 sigma)
#define FB_BLOCKS 782     // ceil(N / 64) feat->bf16 rider blocks (now in bfill)
#define NPB 32            // dst nodes per fuse block
#define FUSE_BLOCKS 1563  // ceil(N / NPB)

typedef __attribute__((ext_vector_type(8))) short bf16x8;   // 8 bf16 in 4 VGPRs
typedef __attribute__((ext_vector_type(4))) float f32x4;

static __host__ __device__ inline size_t align256(size_t x) { return (x + 255) & ~(size_t)255; }

__device__ inline unsigned short f2b(float f) {   // fp32 -> bf16 RNE
    unsigned u = __builtin_bit_cast(unsigned, f);
    unsigned r = (u + 0x7fffu + ((u >> 16) & 1u)) >> 16;
    return (unsigned short)r;
}
__device__ inline float b2f(unsigned short u) {   // bf16 -> fp32
    unsigned v = ((unsigned)u) << 16;
    return __builtin_bit_cast(float, v);
}

// ---------------------------------------------------------------------------
// Kernel 1: blocks [0,NBP) = bucket fill (fixed-capacity regions,
// entry = src|et<<16|dlo<<19, 4096 edges/block);
// blocks [NBP, NBP+FB_BLOCKS) = feat->bf16 (Fb) rider; first 32 riders also
// build WtT[r][f][d] = bf16(W[r][d][f]). Fb/WtT depend on nothing -> moved
// off mid's critical path.
// ---------------------------------------------------------------------------
__global__ void bfill_kernel(const int* __restrict__ dst, const int* __restrict__ srcv,
                             const int* __restrict__ et, const float* __restrict__ W,
                             const float* __restrict__ feat,
                             int* __restrict__ bcnt, int* __restrict__ tmp,
                             unsigned short* __restrict__ WtT,
                             unsigned short* __restrict__ Fb, int E, int N) {
    const int t = threadIdx.x;

    if (blockIdx.x >= NBP) {
        // ------------- Fb rider (+ WtT on first 32 blocks) -------------
        const int fbb = blockIdx.x - NBP;
        if (fbb < 32) {
            int i4 = fbb * 256 + t;           // [0, 8192) float4s of W
            float4 v = ((const float4*)W)[i4];
            int bse = i4 * 4;                 // flat element = (r*64+d)*64 + f
            int f0 = bse & 63;
            int rd = bse >> 6;                // r*64 + d
            int d  = rd & 63;
            int r  = rd >> 6;
            unsigned short* w0 = WtT + ((size_t)(r * 64 + f0) * 64 + d);
            w0[0 * 64] = f2b(v.x);
            w0[1 * 64] = f2b(v.y);
            w0[2 * 64] = f2b(v.z);
            w0[3 * 64] = f2b(v.w);
        }
        const int node = fbb * 64 + (t >> 2);
        if (node >= N) return;
        const int seg = t & 3;
        const float4* F4 = (const float4*)feat + (size_t)node * 16 + seg * 4;
        float4 v0 = F4[0], v1 = F4[1], v2 = F4[2], v3 = F4[3];
        bf16x8 b0, b1;
        b0[0] = (short)f2b(v0.x); b0[1] = (short)f2b(v0.y);
        b0[2] = (short)f2b(v0.z); b0[3] = (short)f2b(v0.w);
        b0[4] = (short)f2b(v1.x); b0[5] = (short)f2b(v1.y);
        b0[6] = (short)f2b(v1.z); b0[7] = (short)f2b(v1.w);
        b1[0] = (short)f2b(v2.x); b1[1] = (short)f2b(v2.y);
        b1[2] = (short)f2b(v2.z); b1[3] = (short)f2b(v2.w);
        b1[4] = (short)f2b(v3.x); b1[5] = (short)f2b(v3.y);
        b1[6] = (short)f2b(v3.z); b1[7] = (short)f2b(v3.w);
        *(bf16x8*)(Fb + (size_t)node * 64 + seg * 16)     = b0;
        *(bf16x8*)(Fb + (size_t)node * 64 + seg * 16 + 8) = b1;
        return;
    }

    // ------------- edge binning half -------------
    __shared__ int hist[256];
    __shared__ int base[256];
    __shared__ int lcur[256];
    hist[t] = 0; lcur[t] = 0;
    __syncthreads();

    const int4* dst4 = (const int4*)dst;
    const int4* src4 = (const int4*)srcv;
    const int4* et4  = (const int4*)et;
    const int n4 = E >> 2;                    // E % 4 == 0
    int bk[16], pk[16];
#pragma unroll
    for (int k = 0; k < 4; k++) {
        int i4 = blockIdx.x * 1024 + t + k * 256;
        if (i4 < n4) {
            int4 d = dst4[i4];
            int4 s = src4[i4];
            int4 r = et4[i4];
            const int dd[4] = {d.x, d.y, d.z, d.w};
            const int ss[4] = {s.x, s.y, s.z, s.w};
            const int rr[4] = {r.x, r.y, r.z, r.w};
#pragma unroll
            for (int j = 0; j < 4; j++) {
                int idx = k * 4 + j;
                bk[idx] = dd[j] >> 8;
                pk[idx] = (ss[j] & 0xFFFF) | (rr[j] << 16) | ((dd[j] & 255) << 19);
                atomicAdd(&hist[bk[idx]], 1);
            }
        } else {
#pragma unroll
            for (int j = 0; j < 4; j++) bk[k * 4 + j] = -1;
        }
    }
    __syncthreads();
    if (t < NBUCK && hist[t] > 0)
        base[t] = t * BCAP + atomicAdd(&bcnt[t], hist[t]);
    __syncthreads();
#pragma unroll
    for (int k = 0; k < 16; k++) {
        if (bk[k] >= 0) {
            int r = atomicAdd(&lcur[bk[k]], 1);
            int pos = base[bk[k]] + r;
            if (pos < (bk[k] + 1) * BCAP)   // memory-safety clamp (never hit)
                tmp[pos] = pk[k];
        }
    }
}

// ---------------------------------------------------------------------------
// Kernel 2: per-bucket counting sort by bin = dlo*8 + rel (2048 bins)
// -> edges of a node are rel-contiguous. Pure sort now (Fb moved to bfill).
// ---------------------------------------------------------------------------
__global__ void mid_kernel(const int* __restrict__ bcnt, const int* __restrict__ tmp,
                           int* __restrict__ spk, int* __restrict__ off_s,
                           int* __restrict__ off_e, int N) {
    __shared__ int hist[2048];
    __shared__ int s[256];
    const int t = threadIdx.x;

    const int b = blockIdx.x;
    const int n0 = b * 256;
    const int nn = min(256, N - n0);
    const int s0 = b * BCAP;
    const int s1 = s0 + min(bcnt[b], BCAP);

#pragma unroll
    for (int j = 0; j < 8; j++) hist[t * 8 + j] = 0;
    __syncthreads();
    // count pass, 4x unrolled for MLP
    for (int i = s0 + t; i < s1; i += 1024) {
        int v0 = tmp[i];
        int v1 = (i + 256 < s1) ? tmp[i + 256] : -1;
        int v2 = (i + 512 < s1) ? tmp[i + 512] : -1;
        int v3 = (i + 768 < s1) ? tmp[i + 768] : -1;
        atomicAdd(&hist[(v0 >> 16) & 0x7FF], 1);
        if (v1 >= 0) atomicAdd(&hist[(v1 >> 16) & 0x7FF], 1);
        if (v2 >= 0) atomicAdd(&hist[(v2 >> 16) & 0x7FF], 1);
        if (v3 >= 0) atomicAdd(&hist[(v3 >> 16) & 0x7FF], 1);
    }
    __syncthreads();
    // two-level scan: thread t owns bins [t*8, t*8+8) = node t's 8 rels
    int loc[8], st[8], T = 0;
#pragma unroll
    for (int j = 0; j < 8; j++) loc[j] = hist[t * 8 + j];
#pragma unroll
    for (int j = 0; j < 8; j++) { st[j] = T; T += loc[j]; }
    s[t] = T;
    __syncthreads();
    for (int o = 1; o < 256; o <<= 1) {
        int u = (t >= o) ? s[t - o] : 0;
        __syncthreads();
        s[t] += u;
        __syncthreads();
    }
    const int base = s0 + s[t] - T;       // exclusive over threads
    if (t < nn) {
        off_s[n0 + t] = base;
        off_e[n0 + t] = base + T;
    }
#pragma unroll
    for (int j = 0; j < 8; j++) hist[t * 8 + j] = base + st[j];
    __syncthreads();
    // scatter pass, 4x unrolled
    for (int i = s0 + t; i < s1; i += 1024) {
        int v0 = tmp[i];
        int v1 = (i + 256 < s1) ? tmp[i + 256] : -1;
        int v2 = (i + 512 < s1) ? tmp[i + 512] : -1;
        int v3 = (i + 768 < s1) ? tmp[i + 768] : -1;
        int p0 = atomicAdd(&hist[(v0 >> 16) & 0x7FF], 1);
        spk[p0] = v0;
        if (v1 >= 0) { int p1 = atomicAdd(&hist[(v1 >> 16) & 0x7FF], 1); spk[p1] = v1; }
        if (v2 >= 0) { int p2 = atomicAdd(&hist[(v2 >> 16) & 0x7FF], 1); spk[p2] = v2; }
        if (v3 >= 0) { int p3 = atomicAdd(&hist[(v3 >> 16) & 0x7FF], 1); spk[p3] = v3; }
    }
}

// ---------------------------------------------------------------------------
// Kernel 3: fused gather-sum -> per-relation MFMA -> epilogue.
// v2 gather: lane-parallel pk preload (kills the spk->Fb dependent chain)
// + 32 static shfls to distribute + 8-deep independent-gather pipeline.
// deg > 32 (P ~ 1e-4 per node) handled by a serial tail.
// ---------------------------------------------------------------------------
__global__ __launch_bounds__(256, 4) void fuse_kernel(
    const int* __restrict__ off_s, const int* __restrict__ off_e,
    const int* __restrict__ spk, const unsigned short* __restrict__ Fb,
    const unsigned short* __restrict__ WtT, const float* __restrict__ feat,
    float* __restrict__ out, int N) {
    __shared__ unsigned short Sb[NRELS][NPB][64];   // 32768 B, swizzled d-blocks
    const int t = threadIdx.x;
    const int n0 = blockIdx.x * NPB;
    const int nn = min(NPB, N - n0);

    // Zero S (covers nodes/rels with no edges).
    {
        f32x4 z = {0.f, 0.f, 0.f, 0.f};
        f32x4* zp = (f32x4*)&Sb[0][0][0];
#pragma unroll
        for (int i = 0; i < 8; i++) zp[t + 256 * i] = z;
    }
    __syncthreads();

    // ---- gather: group gid (8 lanes) owns node n0+gid; lane q owns d-block q.
    const int gid = t >> 3, q = t & 7;
    const int lanebase = (t & 63) & ~7;             // group's lane-0 within wave
    if (gid < nn) {
        const int gn = n0 + gid;
        const int b = off_s[gn], e = off_e[gn];
        const int swz = (q ^ (gid & 7)) * 8;        // physical slot of logical block q
        unsigned short* srow = &Sb[0][0][0] + (size_t)gid * 64 + swz;
        float a[8] = {0.f, 0.f, 0.f, 0.f, 0.f, 0.f, 0.f, 0.f};
        int curR = -1;

        auto flushS = [&](int rel) {
            bf16x8 v;
#pragma unroll
            for (int k = 0; k < 8; k++) v[k] = (short)f2b(a[k]);
            *(bf16x8*)(srow + (size_t)rel * (NPB * 64)) = v;
        };

        // Lane-parallel pk preload: lane q holds edges b+q, b+q+8, b+q+16, b+q+24.
        int pks0 = (b + q      < e) ? spk[b + q]      : -1;
        int pks1 = (b + q + 8  < e) ? spk[b + q + 8]  : -1;
        int pks2 = (b + q + 16 < e) ? spk[b + q + 16] : -1;
        int pks3 = (b + q + 24 < e) ? spk[b + q + 24] : -1;

        // Distribute to group-uniform pkj[0..31] (static shfls -> registers).
        int pkj[32];
#pragma unroll
        for (int j = 0; j < 8; j++) pkj[j]      = __shfl(pks0, lanebase | j);
#pragma unroll
        for (int j = 0; j < 8; j++) pkj[8 + j]  = __shfl(pks1, lanebase | j);
#pragma unroll
        for (int j = 0; j < 8; j++) pkj[16 + j] = __shfl(pks2, lanebase | j);
#pragma unroll
        for (int j = 0; j < 8; j++) pkj[24 + j] = __shfl(pks3, lanebase | j);

        // 8-deep independent gather pipeline.
        bf16x8 u[8];
#pragma unroll
        for (int j = 0; j < 8; j++) {
            u[j] = (bf16x8){0, 0, 0, 0, 0, 0, 0, 0};
            if (pkj[j] >= 0)
                u[j] = *(const bf16x8*)(Fb + (size_t)(pkj[j] & 0xFFFF) * 64 + q * 8);
        }
#pragma unroll
        for (int j = 0; j < 32; j++) {
            bf16x8 uu = u[j & 7];
            if (j + 8 < 32) {                        // refill ring slot with edge j+8
                if (pkj[j + 8] >= 0)
                    u[j & 7] = *(const bf16x8*)(Fb + (size_t)(pkj[j + 8] & 0xFFFF) * 64 + q * 8);
            }
            if (pkj[j] >= 0) {                       // group-uniform predicate
                int rel = (pkj[j] >> 16) & 7;
                if (rel != curR) {
                    if (curR >= 0) flushS(curR);
                    curR = rel;
#pragma unroll
                    for (int k = 0; k < 8; k++) a[k] = 0.f;
                }
#pragma unroll
                for (int k = 0; k < 8; k++) a[k] += b2f((unsigned short)uu[k]);
            }
        }
        // Rare serial tail (deg > 32).
        for (int i = b + 32; i < e; i++) {
            int pk = spk[i];
            bf16x8 uu = *(const bf16x8*)(Fb + (size_t)(pk & 0xFFFF) * 64 + q * 8);
            int rel = (pk >> 16) & 7;
            if (rel != curR) {
                if (curR >= 0) flushS(curR);
                curR = rel;
#pragma unroll
                for (int k = 0; k < 8; k++) a[k] = 0.f;
            }
#pragma unroll
            for (int k = 0; k < 8; k++) a[k] += b2f((unsigned short)uu[k]);
        }
        if (curR >= 0) flushS(curR);
    }
    __syncthreads();

    // ---- MFMA: C[n][f] = sum_r S_r[n][:] @ W_r[:][f]. S is bf16: no f2b here.
    const int w = t >> 6, l = t & 63, col = l & 15, quad = l >> 4;
    f32x4 acc0 = {0.f, 0.f, 0.f, 0.f}, acc1 = {0.f, 0.f, 0.f, 0.f};
    const int sw0 = (quad ^ (col & 7)) * 8;           // logical k-block quad
    const int sw1 = ((quad + 4) ^ (col & 7)) * 8;     // logical k-block quad+4
#pragma unroll
    for (int r = 0; r < NRELS; r++) {
        const unsigned short* wp = WtT + (size_t)r * 4096 + ((w * 16 + col) * 64 + quad * 8);
        bf16x8 b0 = *(const bf16x8*)wp;               // W frags from L2 (hot)
        bf16x8 b1 = *(const bf16x8*)(wp + 32);
        const unsigned short* Sr = &Sb[0][0][0] + (size_t)r * (NPB * 64);
        bf16x8 a0 = *(const bf16x8*)&Sr[col * 64 + sw0];
        bf16x8 a1 = *(const bf16x8*)&Sr[col * 64 + sw1];
        bf16x8 c0 = *(const bf16x8*)&Sr[(16 + col) * 64 + sw0];
        bf16x8 c1 = *(const bf16x8*)&Sr[(16 + col) * 64 + sw1];
        acc0 = __builtin_amdgcn_mfma_f32_16x16x32_bf16(a0, b0, acc0, 0, 0, 0);
        acc0 = __builtin_amdgcn_mfma_f32_16x16x32_bf16(a1, b1, acc0, 0, 0, 0);
        acc1 = __builtin_amdgcn_mfma_f32_16x16x32_bf16(c0, b0, acc1, 0, 0, 0);
        acc1 = __builtin_amdgcn_mfma_f32_16x16x32_bf16(c1, b1, acc1, 0, 0, 0);
    }
    __syncthreads();   // all S reads done -> alias Sb as C bounce [32][72] f32

    float* C = (float*)&Sb[0][0][0];
#pragma unroll
    for (int i = 0; i < 4; i++) {
        C[(quad * 4 + i) * 72 + w * 16 + col]        = acc0[i];
        C[(16 + quad * 4 + i) * 72 + w * 16 + col]   = acc1[i];
    }
    __syncthreads();

    // ---- epilogue: thread t -> node t>>3, f-block t&7 (coalesced).
    {
        const int n = t >> 3;
        if (n < nn) {
            const int gn = n0 + n;
            const int f0 = (t & 7) * 8;
            const int deg = off_e[gn] - off_s[gn];
            float4 m0 = *(const float4*)&C[n * 72 + f0];
            float4 m1 = *(const float4*)&C[n * 72 + f0 + 4];
            const float4* fp = (const float4*)feat + (size_t)gn * 16 + (f0 >> 2);
            float4 h0 = fp[0], h1 = fp[1];
            float4 r0, r1;
            if (deg > 0) {
                float inv = 0.8f / (float)deg;
                r0.x = fmaxf(0.2f * h0.x + m0.x * inv, 0.f);
                r0.y = fmaxf(0.2f * h0.y + m0.y * inv, 0.f);
                r0.z = fmaxf(0.2f * h0.z + m0.z * inv, 0.f);
                r0.w = fmaxf(0.2f * h0.w + m0.w * inv, 0.f);
                r1.x = fmaxf(0.2f * h1.x + m1.x * inv, 0.f);
                r1.y = fmaxf(0.2f * h1.y + m1.y * inv, 0.f);
                r1.z = fmaxf(0.2f * h1.z + m1.z * inv, 0.f);
                r1.w = fmaxf(0.2f * h1.w + m1.w * inv, 0.f);
            } else {
                r0 = h0; r1 = h1;
            }
            float4* op = (float4*)out + (size_t)gn * 16 + (f0 >> 2);
            op[0] = r0;
            op[1] = r1;
        }
    }
}

// ---------------------------------------------------------------------------
// Fallback kernels (small workspace): on-the-fly transform + atomics (fp32).
// ---------------------------------------------------------------------------
__global__ void degf_kernel(const int* __restrict__ dst, float* __restrict__ deg, int E) {
    int e = blockIdx.x * blockDim.x + threadIdx.x;
    if (e < E) atomicAdd(deg + dst[e], 1.0f);
}

__global__ void otf_kernel(const int* __restrict__ src, const int* __restrict__ dst,
                           const int* __restrict__ et, const float* __restrict__ feat,
                           const float* __restrict__ W, float* __restrict__ out, int E) {
    int wid = (blockIdx.x * blockDim.x + threadIdx.x) >> 6;
    int l = threadIdx.x & 63;
    if (wid >= E) return;
    int s = src[wid], dd = dst[wid], r = et[wid];
    float fv = feat[(size_t)s * 64 + l];
    const float* Wr = W + (size_t)r * 4096;
    float acc = 0.f;
#pragma unroll
    for (int d = 0; d < 64; d++) {
        float a = __shfl(fv, d);
        acc += a * Wr[d * 64 + l];
    }
    atomicAdd(out + (size_t)dd * 64 + l, acc);
}

__global__ void final_kernel(const float* __restrict__ feat, const float* __restrict__ deg,
                             float* __restrict__ out, int N) {
    int i = blockIdx.x * blockDim.x + threadIdx.x;
    if (i >= N * 16) return;
    int n = i >> 4;
    float d = deg[n];
    float4 f = ((const float4*)feat)[i];
    float4 m = ((float4*)out)[i];
    float4 res;
    if (d > 0.f) {
        float inv = 0.8f / d;
        res.x = fmaxf(0.2f * f.x + m.x * inv, 0.f);
        res.y = fmaxf(0.2f * f.y + m.y * inv, 0.f);
        res.z = fmaxf(0.2f * f.z + m.z * inv, 0.f);
        res.w = fmaxf(0.2f * f.w + m.w * inv, 0.f);
    } else {
        res = f;
    }
    ((float4*)out)[i] = res;
}

extern "C" void kernel_launch(void* const* d_in, const int* in_sizes, int n_in,
                              void* d_out, int out_size, void* d_ws, size_t ws_size,
                              hipStream_t stream) {
    const float* feat = (const float*)d_in[0];   // [N, 64]
    const float* W    = (const float*)d_in[1];   // [8, 64, 64]
    const int*   src  = (const int*)d_in[2];     // [E]
    const int*   dst  = (const int*)d_in[3];     // [E]
    const int*   et   = (const int*)d_in[4];     // [E]
    float* out = (float*)d_out;                  // [N, 64]

    const int N = N_NODES, E = N_EDGES;

    // Workspace layout:
    char* p = (char*)d_ws;
    int* bcnt  = (int*)p;  p += align256((size_t)NBUCK * 4);
    int* off_s = (int*)p;  p += align256((size_t)N * 4);
    int* off_e = (int*)p;  p += align256((size_t)N * 4);
    int* tmp   = (int*)p;  p += align256((size_t)NBUCK * BCAP * 4);   // 4.0 MB
    int* spk   = (int*)p;  p += align256((size_t)NBUCK * BCAP * 4);   // 4.0 MB
    unsigned short* WtT = (unsigned short*)p;
    p += align256((size_t)NRELS * FEAT * FEAT * 2);                   // 64 KB
    unsigned short* Fb = (unsigned short*)p;
    p += align256((size_t)N * FEAT * 2);                              // 6.4 MB
    size_t need_full = (size_t)(p - (char*)d_ws);

    if (ws_size >= need_full) {
        hipMemsetAsync(bcnt, 0, (size_t)NBUCK * 4, stream);
        bfill_kernel<<<NBP + FB_BLOCKS, 256, 0, stream>>>(dst, src, et, W, feat,
                                                          bcnt, tmp, WtT, Fb, E, N);
        mid_kernel<<<NBUCK, 256, 0, stream>>>(bcnt, tmp, spk, off_s, off_e, N);
        fuse_kernel<<<FUSE_BLOCKS, 256, 0, stream>>>(off_s, off_e, spk, Fb, WtT,
                                                     feat, out, N);
    } else {
        // Minimal-workspace fallback.
        float* deg = (float*)d_ws;
        hipMemsetAsync(out, 0, (size_t)N * FEAT * 4, stream);
        hipMemsetAsync(deg, 0, (size_t)N * 4, stream);
        degf_kernel<<<(E + 255) / 256, 256, 0, stream>>>(dst, deg, E);
        otf_kernel<<<(E + 3) / 4, 256, 0, stream>>>(src, dst, et, feat, W, out, E);
        final_kernel<<<(N * 16 + 255) / 256, 256, 0, stream>>>(feat, deg, out, N);
    }
}